// Round 3
// baseline (678.081 us; speedup 1.0000x reference)
//
#include <hip/hip_runtime.h>
#include <hip/hip_bf16.h>
#include <cstdint>
#include <cstddef>

#define T_DIM 2048
#define C_DIM 1024
#define NH 16
#define HS 64
#define KSP 64

typedef short short8 __attribute__((ext_vector_type(8)));
typedef float f32x4 __attribute__((ext_vector_type(4)));

__device__ __forceinline__ float bfu2f(unsigned short u) {
  unsigned v = ((unsigned)u) << 16;
  return __builtin_bit_cast(float, v);
}
__device__ __forceinline__ unsigned short f2bfu(float f) {
  unsigned u = __builtin_bit_cast(unsigned, f);
  unsigned r = (u + 0x7fffu + ((u >> 16) & 1u)) >> 16;
  return (unsigned short)r;
}

// ---- float32 -> bf16 conversion, 4 elems/thread ----
__global__ __launch_bounds__(256) void convert_kernel(
    const float* __restrict__ src, unsigned short* __restrict__ dst, int n4) {
  const int i = blockIdx.x * 256 + threadIdx.x;
  if (i < n4) {
    float4 f = reinterpret_cast<const float4*>(src)[i];
    ushort4 o;
    o.x = f2bfu(f.x); o.y = f2bfu(f.y); o.z = f2bfu(f.z); o.w = f2bfu(f.w);
    reinterpret_cast<ushort4*>(dst)[i] = o;
  }
}

// ---- key_scores[t] = x[t,:]·Wks + bks  (fp32 exact-ish; one wave per row) ----
__global__ __launch_bounds__(256) void scores_kernel(
    const float* __restrict__ x, const float* __restrict__ Wks,
    const float* __restrict__ bks, float* __restrict__ scores) {
  const int t = blockIdx.x * 4 + (threadIdx.x >> 6);
  const int lane = threadIdx.x & 63;
  const float* xrow = x + (size_t)t * C_DIM;
  float acc = 0.f;
  #pragma unroll 4
  for (int i = lane; i < C_DIM; i += 64)
    acc += xrow[i] * Wks[i];
  #pragma unroll
  for (int o = 32; o; o >>= 1) acc += __shfl_xor(acc, o);
  if (lane == 0) scores[t] = acc + bks[0];
}

// ---- bitonic sort of 2048 (score, idx), descending score, ties -> lower idx ----
__global__ __launch_bounds__(256) void sort_scores_kernel(
    const float* __restrict__ scores, int* __restrict__ sorted_idx) {
  __shared__ float sv[T_DIM];
  __shared__ int si[T_DIM];
  const int tid = threadIdx.x;  // 256 threads
  for (int i = tid; i < T_DIM; i += 256) { sv[i] = scores[i]; si[i] = i; }
  __syncthreads();
  for (int k = 2; k <= T_DIM; k <<= 1) {
    for (int j = k >> 1; j > 0; j >>= 1) {
      for (int i = tid; i < T_DIM; i += 256) {
        int ixj = i ^ j;
        if (ixj > i) {
          bool dir = ((i & k) == 0);
          float s1 = sv[i], s2 = sv[ixj];
          int i1 = si[i], i2 = si[ixj];
          bool b21 = (s2 > s1) || (s2 == s1 && i2 < i1);  // ixj before i
          bool b12 = (s1 > s2) || (s1 == s2 && i1 < i2);  // i before ixj
          if (dir ? b21 : b12) {
            sv[i] = s2; sv[ixj] = s1; si[i] = i2; si[ixj] = i1;
          }
        }
      }
      __syncthreads();
    }
  }
  for (int i = tid; i < T_DIM; i += 256) sorted_idx[i] = si[i];
}

// ---- per-t top-64 selection (set with multiplicity; order irrelevant) ----
__global__ __launch_bounds__(256) void select_topk_kernel(
    const int* __restrict__ sorted_idx, int* __restrict__ topk) {
  __shared__ int ss[T_DIM];
  const int tid = threadIdx.x;
  for (int i = tid; i < T_DIM; i += 256) {
    int s = sorted_idx[i];
    ss[i] = (s < 0) ? 0 : (s > T_DIM - 1 ? T_DIM - 1 : s);  // sanitize
  }
  __syncthreads();
  const int t = blockIdx.x * 256 + tid;
  if (t <= 63) {
    for (int j = 0; j < KSP; ++j) topk[(size_t)t * KSP + j] = (j < t) ? j : t;
  } else {
    int cnt = 0;
    for (int i = 0; i < T_DIM && cnt < KSP; ++i) {
      int s = ss[i];
      if (s <= t) { topk[(size_t)t * KSP + cnt] = s; ++cnt; }
    }
    for (; cnt < KSP; ++cnt) topk[(size_t)t * KSP + cnt] = t;  // insurance
  }
}

// ---- C = A(bf16) · W^T(bf16) + bias(f32) -> bf16; one wave per 16x16 tile ----
__global__ __launch_bounds__(256) void gemm_bt_kernel(
    const unsigned short* __restrict__ A, const unsigned short* __restrict__ W,
    const float* __restrict__ bias, unsigned short* __restrict__ out) {
  const int wid = blockIdx.x * 4 + (threadIdx.x >> 6);
  const int lane = threadIdx.x & 63;
  const int quad = lane >> 4;
  const int r = lane & 15;
  const int ntn = C_DIM / 16;
  const int tm = wid / ntn;
  const int tn = wid % ntn;
  const unsigned short* Ap = A + (size_t)(tm * 16 + r) * C_DIM + quad * 8;
  const unsigned short* Wp = W + (size_t)(tn * 16 + r) * C_DIM + quad * 8;
  f32x4 acc = {0.f, 0.f, 0.f, 0.f};
  #pragma unroll 4
  for (int kk = 0; kk < C_DIM; kk += 32) {
    short8 a = *reinterpret_cast<const short8*>(Ap + kk);
    short8 b = *reinterpret_cast<const short8*>(Wp + kk);
    acc = __builtin_amdgcn_mfma_f32_16x16x32_bf16(a, b, acc, 0, 0, 0);
  }
  const int col = tn * 16 + r;
  const float bf = bias[col];
  #pragma unroll
  for (int i = 0; i < 4; ++i) {
    const int row = tm * 16 + quad * 4 + i;
    out[(size_t)row * C_DIM + col] = f2bfu(acc[i] + bf);
  }
}

// ---- same GEMM but fp32 output (final projection into d_out) ----
__global__ __launch_bounds__(256) void gemm_bt_f32_kernel(
    const unsigned short* __restrict__ A, const unsigned short* __restrict__ W,
    const float* __restrict__ bias, float* __restrict__ out) {
  const int wid = blockIdx.x * 4 + (threadIdx.x >> 6);
  const int lane = threadIdx.x & 63;
  const int quad = lane >> 4;
  const int r = lane & 15;
  const int ntn = C_DIM / 16;
  const int tm = wid / ntn;
  const int tn = wid % ntn;
  const unsigned short* Ap = A + (size_t)(tm * 16 + r) * C_DIM + quad * 8;
  const unsigned short* Wp = W + (size_t)(tn * 16 + r) * C_DIM + quad * 8;
  f32x4 acc = {0.f, 0.f, 0.f, 0.f};
  #pragma unroll 4
  for (int kk = 0; kk < C_DIM; kk += 32) {
    short8 a = *reinterpret_cast<const short8*>(Ap + kk);
    short8 b = *reinterpret_cast<const short8*>(Wp + kk);
    acc = __builtin_amdgcn_mfma_f32_16x16x32_bf16(a, b, acc, 0, 0, 0);
  }
  const int col = tn * 16 + r;
  const float bf = bias[col];
  #pragma unroll
  for (int i = 0; i < 4; ++i) {
    const int row = tm * 16 + quad * 4 + i;
    out[(size_t)row * C_DIM + col] = acc[i] + bf;
  }
}

// ---- sparse attention: block per t, 4 waves x 4 heads each ----
__global__ __launch_bounds__(256) void attn_kernel(
    const unsigned short* __restrict__ q, const unsigned short* __restrict__ k,
    const unsigned short* __restrict__ v, const int* __restrict__ topk,
    unsigned short* __restrict__ attn_out) {
  __shared__ float q_s[C_DIM];
  __shared__ int idx_s[KSP];
  const int t = blockIdx.x;
  const int tid = threadIdx.x;
  for (int i = tid; i < C_DIM; i += 256) q_s[i] = bfu2f(q[(size_t)t * C_DIM + i]);
  if (tid < KSP) {
    int s = topk[(size_t)t * KSP + tid];
    idx_s[tid] = (s < 0) ? 0 : (s > t ? t : s);  // valid set is [0, t]
  }
  __syncthreads();
  const int w = tid >> 6, lane = tid & 63;
  const int my_idx = idx_s[lane];
  const unsigned short* krow_base = k + (size_t)my_idx * C_DIM;
  #pragma unroll
  for (int hh = 0; hh < 4; ++hh) {
    const int h = w * 4 + hh;
    const unsigned short* krow = krow_base + h * HS;
    float lg = 0.f;
    #pragma unroll
    for (int c8 = 0; c8 < 8; ++c8) {
      uint4 raw = *reinterpret_cast<const uint4*>(krow + c8 * 8);
      unsigned uu[4] = {raw.x, raw.y, raw.z, raw.w};
      #pragma unroll
      for (int p = 0; p < 4; ++p) {
        float lo = __builtin_bit_cast(float, uu[p] << 16);
        float hi = __builtin_bit_cast(float, uu[p] & 0xffff0000u);
        lg += q_s[h * HS + c8 * 8 + 2 * p] * lo;
        lg += q_s[h * HS + c8 * 8 + 2 * p + 1] * hi;
      }
    }
    lg *= 0.125f;  // 1/sqrt(64)
    float m = lg;
    #pragma unroll
    for (int o = 32; o; o >>= 1) m = fmaxf(m, __shfl_xor(m, o));
    float pexp = __expf(lg - m);
    float s = pexp;
    #pragma unroll
    for (int o = 32; o; o >>= 1) s += __shfl_xor(s, o);
    const float prob = pexp / s;
    float acc = 0.f;
    const unsigned short* vcol = v + h * HS + lane;
    for (int j = 0; j < KSP; ++j) {
      float pj = __shfl(prob, j);
      int ij = idx_s[j];
      acc += pj * bfu2f(vcol[(size_t)ij * C_DIM]);
    }
    attn_out[(size_t)t * C_DIM + h * HS + lane] = f2bfu(acc);
  }
}

extern "C" void kernel_launch(void* const* d_in, const int* in_sizes, int n_in,
                              void* d_out, int out_size, void* d_ws, size_t ws_size,
                              hipStream_t stream) {
  const float* x   = (const float*)d_in[0];
  const float* Wq  = (const float*)d_in[1];
  const float* bq  = (const float*)d_in[2];
  const float* Wk  = (const float*)d_in[3];
  const float* bk  = (const float*)d_in[4];
  const float* Wv  = (const float*)d_in[5];
  const float* bv  = (const float*)d_in[6];
  const float* Wo  = (const float*)d_in[7];
  const float* bo  = (const float*)d_in[8];
  const float* Wks = (const float*)d_in[9];
  const float* bks = (const float*)d_in[10];
  float* out = (float*)d_out;

  char* ws = (char*)d_ws;
  size_t off = 0;
  float* scores = (float*)(ws + off); off += 8192;
  int*   sorted = (int*)(ws + off);   off += 8192;
  int*   topk   = (int*)(ws + off);   off += (size_t)T_DIM * KSP * 4;   // 512KB
  unsigned short* xb  = (unsigned short*)(ws + off); off += (size_t)T_DIM * C_DIM * 2;  // 4MB
  unsigned short* Wqb = (unsigned short*)(ws + off); off += (size_t)C_DIM * C_DIM * 2;  // 2MB
  unsigned short* Wkb = (unsigned short*)(ws + off); off += (size_t)C_DIM * C_DIM * 2;
  unsigned short* Wvb = (unsigned short*)(ws + off); off += (size_t)C_DIM * C_DIM * 2;
  unsigned short* Wob = (unsigned short*)(ws + off); off += (size_t)C_DIM * C_DIM * 2;
  unsigned short* qb  = (unsigned short*)(ws + off); off += (size_t)T_DIM * C_DIM * 2;
  unsigned short* kb  = (unsigned short*)(ws + off); off += (size_t)T_DIM * C_DIM * 2;
  unsigned short* vb  = (unsigned short*)(ws + off); off += (size_t)T_DIM * C_DIM * 2;
  unsigned short* ab  = (unsigned short*)(ws + off); off += (size_t)T_DIM * C_DIM * 2;

  // bf16 copies of x and weights
  const int nx4 = T_DIM * C_DIM / 4, nw4 = C_DIM * C_DIM / 4;
  convert_kernel<<<(nx4 + 255) / 256, 256, 0, stream>>>(x, xb, nx4);
  convert_kernel<<<(nw4 + 255) / 256, 256, 0, stream>>>(Wq, Wqb, nw4);
  convert_kernel<<<(nw4 + 255) / 256, 256, 0, stream>>>(Wk, Wkb, nw4);
  convert_kernel<<<(nw4 + 255) / 256, 256, 0, stream>>>(Wv, Wvb, nw4);
  convert_kernel<<<(nw4 + 255) / 256, 256, 0, stream>>>(Wo, Wob, nw4);

  // scores (fp32) -> sort -> select
  scores_kernel<<<T_DIM / 4, 256, 0, stream>>>(x, Wks, bks, scores);
  sort_scores_kernel<<<1, 256, 0, stream>>>(scores, sorted);
  select_topk_kernel<<<T_DIM / 256, 256, 0, stream>>>(sorted, topk);

  // QKV projections
  const int gemm_blocks = (T_DIM / 16) * (C_DIM / 16) / 4;  // 2048
  gemm_bt_kernel<<<gemm_blocks, 256, 0, stream>>>(xb, Wqb, bq, qb);
  gemm_bt_kernel<<<gemm_blocks, 256, 0, stream>>>(xb, Wkb, bk, kb);
  gemm_bt_kernel<<<gemm_blocks, 256, 0, stream>>>(xb, Wvb, bv, vb);

  // sparse attention
  attn_kernel<<<T_DIM, 256, 0, stream>>>(qb, kb, vb, topk, ab);

  // output projection (fp32 out)
  gemm_bt_f32_kernel<<<gemm_blocks, 256, 0, stream>>>(ab, Wob, bo, out);
}

// Round 4
// 504.756 us; speedup vs baseline: 1.3434x; 1.3434x over previous
//
#include <hip/hip_runtime.h>
#include <hip/hip_bf16.h>
#include <cstdint>
#include <cstddef>

#define T_DIM 2048
#define C_DIM 1024
#define NH 16
#define HS 64
#define KSP 64

typedef short short8 __attribute__((ext_vector_type(8)));
typedef float f32x4 __attribute__((ext_vector_type(4)));

__device__ __forceinline__ float bfu2f(unsigned short u) {
  unsigned v = ((unsigned)u) << 16;
  return __builtin_bit_cast(float, v);
}
__device__ __forceinline__ unsigned short f2bfu(float f) {
  unsigned u = __builtin_bit_cast(unsigned, f);
  unsigned r = (u + 0x7fffu + ((u >> 16) & 1u)) >> 16;
  return (unsigned short)r;
}

// ---- float32 -> bf16 conversion, 4 elems/thread ----
__global__ __launch_bounds__(256) void convert_kernel(
    const float* __restrict__ src, unsigned short* __restrict__ dst, int n4) {
  const int i = blockIdx.x * 256 + threadIdx.x;
  if (i < n4) {
    float4 f = reinterpret_cast<const float4*>(src)[i];
    ushort4 o;
    o.x = f2bfu(f.x); o.y = f2bfu(f.y); o.z = f2bfu(f.z); o.w = f2bfu(f.w);
    reinterpret_cast<ushort4*>(dst)[i] = o;
  }
}

// ---- key_scores[t] = x[t,:]·Wks + bks  (fp32; one wave per row) ----
__global__ __launch_bounds__(256) void scores_kernel(
    const float* __restrict__ x, const float* __restrict__ Wks,
    const float* __restrict__ bks, float* __restrict__ scores) {
  const int t = blockIdx.x * 4 + (threadIdx.x >> 6);
  const int lane = threadIdx.x & 63;
  const float* xrow = x + (size_t)t * C_DIM;
  float acc = 0.f;
  #pragma unroll 4
  for (int i = lane; i < C_DIM; i += 64)
    acc += xrow[i] * Wks[i];
  #pragma unroll
  for (int o = 32; o; o >>= 1) acc += __shfl_xor(acc, o);
  if (lane == 0) scores[t] = acc + bks[0];
}

// ---- bitonic sort of 2048 (score, idx), descending score, ties -> lower idx ----
__global__ __launch_bounds__(256) void sort_scores_kernel(
    const float* __restrict__ scores, int* __restrict__ sorted_idx) {
  __shared__ float sv[T_DIM];
  __shared__ int si[T_DIM];
  const int tid = threadIdx.x;  // 256 threads
  for (int i = tid; i < T_DIM; i += 256) { sv[i] = scores[i]; si[i] = i; }
  __syncthreads();
  for (int k = 2; k <= T_DIM; k <<= 1) {
    for (int j = k >> 1; j > 0; j >>= 1) {
      for (int i = tid; i < T_DIM; i += 256) {
        int ixj = i ^ j;
        if (ixj > i) {
          bool dir = ((i & k) == 0);
          float s1 = sv[i], s2 = sv[ixj];
          int i1 = si[i], i2 = si[ixj];
          bool b21 = (s2 > s1) || (s2 == s1 && i2 < i1);  // ixj before i
          bool b12 = (s1 > s2) || (s1 == s2 && i1 < i2);  // i before ixj
          if (dir ? b21 : b12) {
            sv[i] = s2; sv[ixj] = s1; si[i] = i2; si[ixj] = i1;
          }
        }
      }
      __syncthreads();
    }
  }
  for (int i = tid; i < T_DIM; i += 256) sorted_idx[i] = si[i];
}

// ---- per-t top-64 selection: ONE WAVE PER t, ballot + prefix-popcount ----
__global__ __launch_bounds__(256) void select_topk_kernel(
    const int* __restrict__ sorted_idx, int* __restrict__ topk) {
  __shared__ int ss[T_DIM];
  const int tid = threadIdx.x;
  for (int i = tid; i < T_DIM; i += 256) {
    int s = sorted_idx[i];
    ss[i] = (s < 0) ? 0 : (s > T_DIM - 1 ? T_DIM - 1 : s);  // sanitize
  }
  __syncthreads();
  const int t = blockIdx.x * 4 + (tid >> 6);  // one wave per row t
  const int lane = tid & 63;
  if (t <= 63) {
    // valid set {0..t} + clamped copies of t  == min(lane, t)
    topk[(size_t)t * KSP + lane] = (lane < t) ? lane : t;
  } else {
    // compact first 64 entries of sorted list with idx <= t
    const unsigned long long lt_mask = (1ull << lane) - 1ull;
    int count = 0;
    for (int chunk = 0; chunk < T_DIM / 64 && count < KSP; ++chunk) {
      int s = ss[chunk * 64 + lane];
      bool ok = (s <= t);
      unsigned long long m = __ballot(ok);
      int pos = count + __popcll(m & lt_mask);
      if (ok && pos < KSP) topk[(size_t)t * KSP + pos] = s;
      count += __popcll(m);  // wave-uniform
    }
    // t >= 64 guarantees >= 65 valid entries -> count >= 64 always reached
  }
}

// ---- C = A(bf16) · W^T(bf16) + bias(f32) -> bf16; one wave per 16x16 tile ----
__global__ __launch_bounds__(256) void gemm_bt_kernel(
    const unsigned short* __restrict__ A, const unsigned short* __restrict__ W,
    const float* __restrict__ bias, unsigned short* __restrict__ out) {
  const int wid = blockIdx.x * 4 + (threadIdx.x >> 6);
  const int lane = threadIdx.x & 63;
  const int quad = lane >> 4;
  const int r = lane & 15;
  const int ntn = C_DIM / 16;
  const int tm = wid / ntn;
  const int tn = wid % ntn;
  const unsigned short* Ap = A + (size_t)(tm * 16 + r) * C_DIM + quad * 8;
  const unsigned short* Wp = W + (size_t)(tn * 16 + r) * C_DIM + quad * 8;
  f32x4 acc = {0.f, 0.f, 0.f, 0.f};
  #pragma unroll 4
  for (int kk = 0; kk < C_DIM; kk += 32) {
    short8 a = *reinterpret_cast<const short8*>(Ap + kk);
    short8 b = *reinterpret_cast<const short8*>(Wp + kk);
    acc = __builtin_amdgcn_mfma_f32_16x16x32_bf16(a, b, acc, 0, 0, 0);
  }
  const int col = tn * 16 + r;
  const float bf = bias[col];
  #pragma unroll
  for (int i = 0; i < 4; ++i) {
    const int row = tm * 16 + quad * 4 + i;
    out[(size_t)row * C_DIM + col] = f2bfu(acc[i] + bf);
  }
}

// ---- same GEMM but fp32 output (final projection into d_out) ----
__global__ __launch_bounds__(256) void gemm_bt_f32_kernel(
    const unsigned short* __restrict__ A, const unsigned short* __restrict__ W,
    const float* __restrict__ bias, float* __restrict__ out) {
  const int wid = blockIdx.x * 4 + (threadIdx.x >> 6);
  const int lane = threadIdx.x & 63;
  const int quad = lane >> 4;
  const int r = lane & 15;
  const int ntn = C_DIM / 16;
  const int tm = wid / ntn;
  const int tn = wid % ntn;
  const unsigned short* Ap = A + (size_t)(tm * 16 + r) * C_DIM + quad * 8;
  const unsigned short* Wp = W + (size_t)(tn * 16 + r) * C_DIM + quad * 8;
  f32x4 acc = {0.f, 0.f, 0.f, 0.f};
  #pragma unroll 4
  for (int kk = 0; kk < C_DIM; kk += 32) {
    short8 a = *reinterpret_cast<const short8*>(Ap + kk);
    short8 b = *reinterpret_cast<const short8*>(Wp + kk);
    acc = __builtin_amdgcn_mfma_f32_16x16x32_bf16(a, b, acc, 0, 0, 0);
  }
  const int col = tn * 16 + r;
  const float bf = bias[col];
  #pragma unroll
  for (int i = 0; i < 4; ++i) {
    const int row = tm * 16 + quad * 4 + i;
    out[(size_t)row * C_DIM + col] = acc[i] + bf;
  }
}

// ---- sparse attention: block per t, 4 waves x 4 heads each ----
__global__ __launch_bounds__(256) void attn_kernel(
    const unsigned short* __restrict__ q, const unsigned short* __restrict__ k,
    const unsigned short* __restrict__ v, const int* __restrict__ topk,
    unsigned short* __restrict__ attn_out) {
  __shared__ float q_s[C_DIM];
  __shared__ int idx_s[KSP];
  const int t = blockIdx.x;
  const int tid = threadIdx.x;
  for (int i = tid; i < C_DIM; i += 256) q_s[i] = bfu2f(q[(size_t)t * C_DIM + i]);
  if (tid < KSP) {
    int s = topk[(size_t)t * KSP + tid];
    idx_s[tid] = (s < 0) ? 0 : (s > t ? t : s);  // valid set is [0, t]
  }
  __syncthreads();
  const int w = tid >> 6, lane = tid & 63;
  const int my_idx = idx_s[lane];
  const unsigned short* krow_base = k + (size_t)my_idx * C_DIM;
  #pragma unroll
  for (int hh = 0; hh < 4; ++hh) {
    const int h = w * 4 + hh;
    const unsigned short* krow = krow_base + h * HS;
    float lg = 0.f;
    #pragma unroll
    for (int c8 = 0; c8 < 8; ++c8) {
      uint4 raw = *reinterpret_cast<const uint4*>(krow + c8 * 8);
      unsigned uu[4] = {raw.x, raw.y, raw.z, raw.w};
      #pragma unroll
      for (int p = 0; p < 4; ++p) {
        float lo = __builtin_bit_cast(float, uu[p] << 16);
        float hi = __builtin_bit_cast(float, uu[p] & 0xffff0000u);
        lg += q_s[h * HS + c8 * 8 + 2 * p] * lo;
        lg += q_s[h * HS + c8 * 8 + 2 * p + 1] * hi;
      }
    }
    lg *= 0.125f;  // 1/sqrt(64)
    float m = lg;
    #pragma unroll
    for (int o = 32; o; o >>= 1) m = fmaxf(m, __shfl_xor(m, o));
    float pexp = __expf(lg - m);
    float s = pexp;
    #pragma unroll
    for (int o = 32; o; o >>= 1) s += __shfl_xor(s, o);
    const float prob = pexp / s;
    float acc = 0.f;
    const unsigned short* vcol = v + h * HS + lane;
    for (int j = 0; j < KSP; ++j) {
      float pj = __shfl(prob, j);
      int ij = idx_s[j];
      acc += pj * bfu2f(vcol[(size_t)ij * C_DIM]);
    }
    attn_out[(size_t)t * C_DIM + h * HS + lane] = f2bfu(acc);
  }
}

extern "C" void kernel_launch(void* const* d_in, const int* in_sizes, int n_in,
                              void* d_out, int out_size, void* d_ws, size_t ws_size,
                              hipStream_t stream) {
  const float* x   = (const float*)d_in[0];
  const float* Wq  = (const float*)d_in[1];
  const float* bq  = (const float*)d_in[2];
  const float* Wk  = (const float*)d_in[3];
  const float* bk  = (const float*)d_in[4];
  const float* Wv  = (const float*)d_in[5];
  const float* bv  = (const float*)d_in[6];
  const float* Wo  = (const float*)d_in[7];
  const float* bo  = (const float*)d_in[8];
  const float* Wks = (const float*)d_in[9];
  const float* bks = (const float*)d_in[10];
  float* out = (float*)d_out;

  char* ws = (char*)d_ws;
  size_t off = 0;
  float* scores = (float*)(ws + off); off += 8192;
  int*   sorted = (int*)(ws + off);   off += 8192;
  int*   topk   = (int*)(ws + off);   off += (size_t)T_DIM * KSP * 4;   // 512KB
  unsigned short* xb  = (unsigned short*)(ws + off); off += (size_t)T_DIM * C_DIM * 2;  // 4MB
  unsigned short* Wqb = (unsigned short*)(ws + off); off += (size_t)C_DIM * C_DIM * 2;  // 2MB
  unsigned short* Wkb = (unsigned short*)(ws + off); off += (size_t)C_DIM * C_DIM * 2;
  unsigned short* Wvb = (unsigned short*)(ws + off); off += (size_t)C_DIM * C_DIM * 2;
  unsigned short* Wob = (unsigned short*)(ws + off); off += (size_t)C_DIM * C_DIM * 2;
  unsigned short* qb  = (unsigned short*)(ws + off); off += (size_t)T_DIM * C_DIM * 2;
  unsigned short* kb  = (unsigned short*)(ws + off); off += (size_t)T_DIM * C_DIM * 2;
  unsigned short* vb  = (unsigned short*)(ws + off); off += (size_t)T_DIM * C_DIM * 2;
  unsigned short* ab  = (unsigned short*)(ws + off); off += (size_t)T_DIM * C_DIM * 2;

  // bf16 copies of x and weights
  const int nx4 = T_DIM * C_DIM / 4, nw4 = C_DIM * C_DIM / 4;
  convert_kernel<<<(nx4 + 255) / 256, 256, 0, stream>>>(x, xb, nx4);
  convert_kernel<<<(nw4 + 255) / 256, 256, 0, stream>>>(Wq, Wqb, nw4);
  convert_kernel<<<(nw4 + 255) / 256, 256, 0, stream>>>(Wk, Wkb, nw4);
  convert_kernel<<<(nw4 + 255) / 256, 256, 0, stream>>>(Wv, Wvb, nw4);
  convert_kernel<<<(nw4 + 255) / 256, 256, 0, stream>>>(Wo, Wob, nw4);

  // scores (fp32) -> sort -> select
  scores_kernel<<<T_DIM / 4, 256, 0, stream>>>(x, Wks, bks, scores);
  sort_scores_kernel<<<1, 256, 0, stream>>>(scores, sorted);
  select_topk_kernel<<<T_DIM / 4, 256, 0, stream>>>(sorted, topk);

  // QKV projections
  const int gemm_blocks = (T_DIM / 16) * (C_DIM / 16) / 4;  // 2048
  gemm_bt_kernel<<<gemm_blocks, 256, 0, stream>>>(xb, Wqb, bq, qb);
  gemm_bt_kernel<<<gemm_blocks, 256, 0, stream>>>(xb, Wkb, bk, kb);
  gemm_bt_kernel<<<gemm_blocks, 256, 0, stream>>>(xb, Wvb, bv, vb);

  // sparse attention
  attn_kernel<<<T_DIM, 256, 0, stream>>>(qb, kb, vb, topk, ab);

  // output projection (fp32 out)
  gemm_bt_f32_kernel<<<gemm_blocks, 256, 0, stream>>>(ab, Wob, bo, out);
}

// Round 5
// 274.472 us; speedup vs baseline: 2.4705x; 1.8390x over previous
//
#include <hip/hip_runtime.h>
#include <hip/hip_bf16.h>
#include <cstdint>
#include <cstddef>

#define T_DIM 2048
#define C_DIM 1024
#define NH 16
#define HS 64
#define KSP 64

#define BM 64
#define BN 64
#define BK 64
#define LPAD 72  // 64 + 8 bf16 -> 144B row stride (16B-aligned, 2-way bank alias only)

typedef short short8 __attribute__((ext_vector_type(8)));
typedef float f32x4 __attribute__((ext_vector_type(4)));

__device__ __forceinline__ float bfu2f(unsigned short u) {
  unsigned v = ((unsigned)u) << 16;
  return __builtin_bit_cast(float, v);
}
__device__ __forceinline__ unsigned short f2bfu(float f) {
  unsigned u = __builtin_bit_cast(unsigned, f);
  unsigned r = (u + 0x7fffu + ((u >> 16) & 1u)) >> 16;
  return (unsigned short)r;
}

// ---- float32 -> bf16 conversion, 4 elems/thread ----
__global__ __launch_bounds__(256) void convert_kernel(
    const float* __restrict__ src, unsigned short* __restrict__ dst, int n4) {
  const int i = blockIdx.x * 256 + threadIdx.x;
  if (i < n4) {
    float4 f = reinterpret_cast<const float4*>(src)[i];
    ushort4 o;
    o.x = f2bfu(f.x); o.y = f2bfu(f.y); o.z = f2bfu(f.z); o.w = f2bfu(f.w);
    reinterpret_cast<ushort4*>(dst)[i] = o;
  }
}

// ---- key_scores[t] = x[t,:]·Wks + bks  (fp32; one wave per row) ----
__global__ __launch_bounds__(256) void scores_kernel(
    const float* __restrict__ x, const float* __restrict__ Wks,
    const float* __restrict__ bks, float* __restrict__ scores) {
  const int t = blockIdx.x * 4 + (threadIdx.x >> 6);
  const int lane = threadIdx.x & 63;
  const float* xrow = x + (size_t)t * C_DIM;
  float acc = 0.f;
  #pragma unroll 4
  for (int i = lane; i < C_DIM; i += 64)
    acc += xrow[i] * Wks[i];
  #pragma unroll
  for (int o = 32; o; o >>= 1) acc += __shfl_xor(acc, o);
  if (lane == 0) scores[t] = acc + bks[0];
}

// ---- rank-by-counting sort: sorted[rank_i] = i; no syncthreads in hot loop ----
__global__ __launch_bounds__(256) void rank_sort_kernel(
    const float* __restrict__ scores, int* __restrict__ sorted_idx) {
  __shared__ float ss[T_DIM];
  const int tid = threadIdx.x;
  const int i = blockIdx.x * 256 + tid;  // grid = 8 blocks -> i in [0,2048)
  for (int j = tid; j < T_DIM; j += 256) ss[j] = scores[j];
  __syncthreads();
  const float si = ss[i];
  int rank = 0;
  #pragma unroll 8
  for (int j = 0; j < T_DIM; ++j) {
    float sj = ss[j];
    rank += (int)((sj > si) || (sj == si && j < i));
  }
  sorted_idx[rank] = i;
}

// ---- per-t top-64 selection: ONE WAVE PER t, ballot + prefix-popcount ----
__global__ __launch_bounds__(256) void select_topk_kernel(
    const int* __restrict__ sorted_idx, int* __restrict__ topk) {
  __shared__ int ss[T_DIM];
  const int tid = threadIdx.x;
  for (int i = tid; i < T_DIM; i += 256) {
    int s = sorted_idx[i];
    ss[i] = (s < 0) ? 0 : (s > T_DIM - 1 ? T_DIM - 1 : s);  // sanitize
  }
  __syncthreads();
  const int t = blockIdx.x * 4 + (tid >> 6);  // one wave per row t
  const int lane = tid & 63;
  if (t <= 63) {
    topk[(size_t)t * KSP + lane] = (lane < t) ? lane : t;
  } else {
    const unsigned long long lt_mask = (1ull << lane) - 1ull;
    int count = 0;
    for (int chunk = 0; chunk < T_DIM / 64 && count < KSP; ++chunk) {
      int s = ss[chunk * 64 + lane];
      bool ok = (s <= t);
      unsigned long long m = __ballot(ok);
      int pos = count + __popcll(m & lt_mask);
      if (ok && pos < KSP) topk[(size_t)t * KSP + pos] = s;
      count += __popcll(m);  // wave-uniform
    }
  }
}

// ---- LDS-tiled GEMM: C = A(bf16, MxK) · W^T(bf16 NxK) + bias; 64x64/block,
// 4 waves x (32x32 out: 2x2 mfma_16x16x32), BK=64 ----
__device__ __forceinline__ void gemm_tile_body(
    const unsigned short* __restrict__ A, const unsigned short* __restrict__ W,
    f32x4 acc[2][2], int bm, int bn, int tid) {
  __shared__ unsigned short As[BM][LPAD];
  __shared__ unsigned short Ws[BN][LPAD];
  const int w = tid >> 6, lane = tid & 63;
  const int quad = lane >> 4, r = lane & 15;
  const int wm = (w >> 1) * 32, wn = (w & 1) * 32;
  const int lr = tid >> 3;          // 0..31
  const int lc = (tid & 7) * 8;     // 0..56
  const unsigned short* Abase = A + (size_t)(bm * BM + lr) * C_DIM + lc;
  const unsigned short* Wbase = W + (size_t)(bn * BN + lr) * C_DIM + lc;
  for (int kb = 0; kb < C_DIM; kb += BK) {
    *reinterpret_cast<short8*>(&As[lr][lc]) =
        *reinterpret_cast<const short8*>(Abase + kb);
    *reinterpret_cast<short8*>(&As[lr + 32][lc]) =
        *reinterpret_cast<const short8*>(Abase + kb + 32 * C_DIM);
    *reinterpret_cast<short8*>(&Ws[lr][lc]) =
        *reinterpret_cast<const short8*>(Wbase + kb);
    *reinterpret_cast<short8*>(&Ws[lr + 32][lc]) =
        *reinterpret_cast<const short8*>(Wbase + kb + 32 * C_DIM);
    __syncthreads();
    #pragma unroll
    for (int ks = 0; ks < BK; ks += 32) {
      short8 a0 = *reinterpret_cast<const short8*>(&As[wm + r][ks + quad * 8]);
      short8 a1 = *reinterpret_cast<const short8*>(&As[wm + 16 + r][ks + quad * 8]);
      short8 b0 = *reinterpret_cast<const short8*>(&Ws[wn + r][ks + quad * 8]);
      short8 b1 = *reinterpret_cast<const short8*>(&Ws[wn + 16 + r][ks + quad * 8]);
      acc[0][0] = __builtin_amdgcn_mfma_f32_16x16x32_bf16(a0, b0, acc[0][0], 0, 0, 0);
      acc[0][1] = __builtin_amdgcn_mfma_f32_16x16x32_bf16(a0, b1, acc[0][1], 0, 0, 0);
      acc[1][0] = __builtin_amdgcn_mfma_f32_16x16x32_bf16(a1, b0, acc[1][0], 0, 0, 0);
      acc[1][1] = __builtin_amdgcn_mfma_f32_16x16x32_bf16(a1, b1, acc[1][1], 0, 0, 0);
    }
    __syncthreads();
  }
}

__global__ __launch_bounds__(256) void gemm_tile_bf16_kernel(
    const unsigned short* __restrict__ A, const unsigned short* __restrict__ W,
    const float* __restrict__ bias, unsigned short* __restrict__ out) {
  const int tid = threadIdx.x;
  const int bm = blockIdx.x / (C_DIM / BN);
  const int bn = blockIdx.x % (C_DIM / BN);
  f32x4 acc[2][2] = {};
  gemm_tile_body(A, W, acc, bm, bn, tid);
  const int w = tid >> 6, lane = tid & 63;
  const int quad = lane >> 4, r = lane & 15;
  const int wm = (w >> 1) * 32, wn = (w & 1) * 32;
  #pragma unroll
  for (int mi = 0; mi < 2; ++mi) {
    #pragma unroll
    for (int ni = 0; ni < 2; ++ni) {
      const int col = bn * BN + wn + ni * 16 + r;
      const float bf = bias[col];
      #pragma unroll
      for (int i = 0; i < 4; ++i) {
        const int row = bm * BM + wm + mi * 16 + quad * 4 + i;
        out[(size_t)row * C_DIM + col] = f2bfu(acc[mi][ni][i] + bf);
      }
    }
  }
}

__global__ __launch_bounds__(256) void gemm_tile_f32_kernel(
    const unsigned short* __restrict__ A, const unsigned short* __restrict__ W,
    const float* __restrict__ bias, float* __restrict__ out) {
  const int tid = threadIdx.x;
  const int bm = blockIdx.x / (C_DIM / BN);
  const int bn = blockIdx.x % (C_DIM / BN);
  f32x4 acc[2][2] = {};
  gemm_tile_body(A, W, acc, bm, bn, tid);
  const int w = tid >> 6, lane = tid & 63;
  const int quad = lane >> 4, r = lane & 15;
  const int wm = (w >> 1) * 32, wn = (w & 1) * 32;
  #pragma unroll
  for (int mi = 0; mi < 2; ++mi) {
    #pragma unroll
    for (int ni = 0; ni < 2; ++ni) {
      const int col = bn * BN + wn + ni * 16 + r;
      const float bf = bias[col];
      #pragma unroll
      for (int i = 0; i < 4; ++i) {
        const int row = bm * BM + wm + mi * 16 + quad * 4 + i;
        out[(size_t)row * C_DIM + col] = acc[mi][ni][i] + bf;
      }
    }
  }
}

// ---- sparse attention: block per t, 4 waves x 4 heads each ----
__global__ __launch_bounds__(256) void attn_kernel(
    const unsigned short* __restrict__ q, const unsigned short* __restrict__ k,
    const unsigned short* __restrict__ v, const int* __restrict__ topk,
    unsigned short* __restrict__ attn_out) {
  __shared__ float q_s[C_DIM];
  __shared__ int idx_s[KSP];
  const int t = blockIdx.x;
  const int tid = threadIdx.x;
  for (int i = tid; i < C_DIM; i += 256) q_s[i] = bfu2f(q[(size_t)t * C_DIM + i]);
  if (tid < KSP) {
    int s = topk[(size_t)t * KSP + tid];
    idx_s[tid] = (s < 0) ? 0 : (s > t ? t : s);  // valid set is [0, t]
  }
  __syncthreads();
  const int w = tid >> 6, lane = tid & 63;
  const int my_idx = idx_s[lane];
  const unsigned short* krow_base = k + (size_t)my_idx * C_DIM;
  #pragma unroll
  for (int hh = 0; hh < 4; ++hh) {
    const int h = w * 4 + hh;
    const unsigned short* krow = krow_base + h * HS;
    float lg = 0.f;
    #pragma unroll
    for (int c8 = 0; c8 < 8; ++c8) {
      uint4 raw = *reinterpret_cast<const uint4*>(krow + c8 * 8);
      unsigned uu[4] = {raw.x, raw.y, raw.z, raw.w};
      #pragma unroll
      for (int p = 0; p < 4; ++p) {
        float lo = __builtin_bit_cast(float, uu[p] << 16);
        float hi = __builtin_bit_cast(float, uu[p] & 0xffff0000u);
        lg += q_s[h * HS + c8 * 8 + 2 * p] * lo;
        lg += q_s[h * HS + c8 * 8 + 2 * p + 1] * hi;
      }
    }
    lg *= 0.125f;  // 1/sqrt(64)
    float m = lg;
    #pragma unroll
    for (int o = 32; o; o >>= 1) m = fmaxf(m, __shfl_xor(m, o));
    float pexp = __expf(lg - m);
    float s = pexp;
    #pragma unroll
    for (int o = 32; o; o >>= 1) s += __shfl_xor(s, o);
    const float prob = pexp / s;
    float acc = 0.f;
    const unsigned short* vcol = v + h * HS + lane;
    for (int j = 0; j < KSP; ++j) {
      float pj = __shfl(prob, j);
      int ij = idx_s[j];
      acc += pj * bfu2f(vcol[(size_t)ij * C_DIM]);
    }
    attn_out[(size_t)t * C_DIM + h * HS + lane] = f2bfu(acc);
  }
}

extern "C" void kernel_launch(void* const* d_in, const int* in_sizes, int n_in,
                              void* d_out, int out_size, void* d_ws, size_t ws_size,
                              hipStream_t stream) {
  const float* x   = (const float*)d_in[0];
  const float* Wq  = (const float*)d_in[1];
  const float* bq  = (const float*)d_in[2];
  const float* Wk  = (const float*)d_in[3];
  const float* bk  = (const float*)d_in[4];
  const float* Wv  = (const float*)d_in[5];
  const float* bv  = (const float*)d_in[6];
  const float* Wo  = (const float*)d_in[7];
  const float* bo  = (const float*)d_in[8];
  const float* Wks = (const float*)d_in[9];
  const float* bks = (const float*)d_in[10];
  float* out = (float*)d_out;

  char* ws = (char*)d_ws;
  size_t off = 0;
  float* scores = (float*)(ws + off); off += 8192;
  int*   sorted = (int*)(ws + off);   off += 8192;
  int*   topk   = (int*)(ws + off);   off += (size_t)T_DIM * KSP * 4;   // 512KB
  unsigned short* xb  = (unsigned short*)(ws + off); off += (size_t)T_DIM * C_DIM * 2;  // 4MB
  unsigned short* Wqb = (unsigned short*)(ws + off); off += (size_t)C_DIM * C_DIM * 2;  // 2MB
  unsigned short* Wkb = (unsigned short*)(ws + off); off += (size_t)C_DIM * C_DIM * 2;
  unsigned short* Wvb = (unsigned short*)(ws + off); off += (size_t)C_DIM * C_DIM * 2;
  unsigned short* Wob = (unsigned short*)(ws + off); off += (size_t)C_DIM * C_DIM * 2;
  unsigned short* qb  = (unsigned short*)(ws + off); off += (size_t)T_DIM * C_DIM * 2;
  unsigned short* kb  = (unsigned short*)(ws + off); off += (size_t)T_DIM * C_DIM * 2;
  unsigned short* vb  = (unsigned short*)(ws + off); off += (size_t)T_DIM * C_DIM * 2;
  unsigned short* ab  = (unsigned short*)(ws + off); off += (size_t)T_DIM * C_DIM * 2;

  // bf16 copies of x and weights
  const int nx4 = T_DIM * C_DIM / 4, nw4 = C_DIM * C_DIM / 4;
  convert_kernel<<<(nx4 + 255) / 256, 256, 0, stream>>>(x, xb, nx4);
  convert_kernel<<<(nw4 + 255) / 256, 256, 0, stream>>>(Wq, Wqb, nw4);
  convert_kernel<<<(nw4 + 255) / 256, 256, 0, stream>>>(Wk, Wkb, nw4);
  convert_kernel<<<(nw4 + 255) / 256, 256, 0, stream>>>(Wv, Wvb, nw4);
  convert_kernel<<<(nw4 + 255) / 256, 256, 0, stream>>>(Wo, Wob, nw4);

  // scores (fp32) -> rank-sort -> select
  scores_kernel<<<T_DIM / 4, 256, 0, stream>>>(x, Wks, bks, scores);
  rank_sort_kernel<<<T_DIM / 256, 256, 0, stream>>>(scores, sorted);
  select_topk_kernel<<<T_DIM / 4, 256, 0, stream>>>(sorted, topk);

  // QKV projections (tiled)
  const int gemm_blocks = (T_DIM / BM) * (C_DIM / BN);  // 512
  gemm_tile_bf16_kernel<<<gemm_blocks, 256, 0, stream>>>(xb, Wqb, bq, qb);
  gemm_tile_bf16_kernel<<<gemm_blocks, 256, 0, stream>>>(xb, Wkb, bk, kb);
  gemm_tile_bf16_kernel<<<gemm_blocks, 256, 0, stream>>>(xb, Wvb, bv, vb);

  // sparse attention
  attn_kernel<<<T_DIM, 256, 0, stream>>>(qb, kb, vb, topk, ab);

  // output projection (fp32 out)
  gemm_tile_f32_kernel<<<gemm_blocks, 256, 0, stream>>>(ab, Wob, bo, out);
}

// Round 6
// 244.546 us; speedup vs baseline: 2.7728x; 1.1224x over previous
//
#include <hip/hip_runtime.h>
#include <hip/hip_bf16.h>
#include <cstdint>
#include <cstddef>

#define T_DIM 2048
#define C_DIM 1024
#define NH 16
#define HS 64
#define KSP 64

#define BM 64
#define BN 64
#define BK 64
#define LPAD 72  // 64 + 8 bf16 -> 144B row stride (16B-aligned, 2-way bank alias only)

typedef short short8 __attribute__((ext_vector_type(8)));
typedef float f32x4 __attribute__((ext_vector_type(4)));

__device__ __forceinline__ float bfu2f(unsigned short u) {
  unsigned v = ((unsigned)u) << 16;
  return __builtin_bit_cast(float, v);
}
__device__ __forceinline__ unsigned short f2bfu(float f) {
  unsigned u = __builtin_bit_cast(unsigned, f);
  unsigned r = (u + 0x7fffu + ((u >> 16) & 1u)) >> 16;
  return (unsigned short)r;
}

// ---- fused float32 -> bf16 conversion of x + 4 weight matrices ----
// layout: [x: 512K float4][Wq: 256K][Wk: 256K][Wv: 256K][Wo: 256K]
__global__ __launch_bounds__(256) void convert_all_kernel(
    const float* __restrict__ x, const float* __restrict__ Wq,
    const float* __restrict__ Wk, const float* __restrict__ Wv,
    const float* __restrict__ Wo,
    unsigned short* __restrict__ xb, unsigned short* __restrict__ Wqb,
    unsigned short* __restrict__ Wkb, unsigned short* __restrict__ Wvb,
    unsigned short* __restrict__ Wob) {
  const int i = blockIdx.x * 256 + threadIdx.x;  // float4 index, [0, 1572864)
  const int NX4 = T_DIM * C_DIM / 4;             // 524288
  const int NW4 = C_DIM * C_DIM / 4;             // 262144
  const float* src;
  unsigned short* dst;
  int j = i;
  if (j < NX4) { src = x; dst = xb; }
  else {
    j -= NX4;
    int w = j / NW4;  // 0..3
    j -= w * NW4;
    src = (w == 0) ? Wq : (w == 1) ? Wk : (w == 2) ? Wv : Wo;
    dst = (w == 0) ? Wqb : (w == 1) ? Wkb : (w == 2) ? Wvb : Wob;
  }
  float4 f = reinterpret_cast<const float4*>(src)[j];
  ushort4 o;
  o.x = f2bfu(f.x); o.y = f2bfu(f.y); o.z = f2bfu(f.z); o.w = f2bfu(f.w);
  reinterpret_cast<ushort4*>(dst)[j] = o;
}

// ---- key_scores[t] = x[t,:]·Wks + bks  (fp32; one wave per row) ----
__global__ __launch_bounds__(256) void scores_kernel(
    const float* __restrict__ x, const float* __restrict__ Wks,
    const float* __restrict__ bks, float* __restrict__ scores) {
  const int t = blockIdx.x * 4 + (threadIdx.x >> 6);
  const int lane = threadIdx.x & 63;
  const float* xrow = x + (size_t)t * C_DIM;
  float acc = 0.f;
  #pragma unroll 4
  for (int i = lane; i < C_DIM; i += 64)
    acc += xrow[i] * Wks[i];
  #pragma unroll
  for (int o = 32; o; o >>= 1) acc += __shfl_xor(acc, o);
  if (lane == 0) scores[t] = acc + bks[0];
}

// ---- rank-by-counting sort: sorted[rank_i] = i ----
__global__ __launch_bounds__(256) void rank_sort_kernel(
    const float* __restrict__ scores, int* __restrict__ sorted_idx) {
  __shared__ float ss[T_DIM];
  const int tid = threadIdx.x;
  const int i = blockIdx.x * 256 + tid;
  for (int j = tid; j < T_DIM; j += 256) ss[j] = scores[j];
  __syncthreads();
  const float si = ss[i];
  int rank = 0;
  #pragma unroll 8
  for (int j = 0; j < T_DIM; ++j) {
    float sj = ss[j];
    rank += (int)((sj > si) || (sj == si && j < i));
  }
  sorted_idx[rank] = i;
}

// ---- per-t top-64 selection: one wave per t, ballot + prefix-popcount ----
__global__ __launch_bounds__(256) void select_topk_kernel(
    const int* __restrict__ sorted_idx, int* __restrict__ topk) {
  __shared__ int ss[T_DIM];
  const int tid = threadIdx.x;
  for (int i = tid; i < T_DIM; i += 256) {
    int s = sorted_idx[i];
    ss[i] = (s < 0) ? 0 : (s > T_DIM - 1 ? T_DIM - 1 : s);
  }
  __syncthreads();
  const int t = blockIdx.x * 4 + (tid >> 6);
  const int lane = tid & 63;
  if (t <= 63) {
    topk[(size_t)t * KSP + lane] = (lane < t) ? lane : t;
  } else {
    const unsigned long long lt_mask = (1ull << lane) - 1ull;
    int count = 0;
    for (int chunk = 0; chunk < T_DIM / 64 && count < KSP; ++chunk) {
      int s = ss[chunk * 64 + lane];
      bool ok = (s <= t);
      unsigned long long m = __ballot(ok);
      int pos = count + __popcll(m & lt_mask);
      if (ok && pos < KSP) topk[(size_t)t * KSP + pos] = s;
      count += __popcll(m);
    }
  }
}

// ---- LDS-tiled GEMM body: 64x64/block, 4 waves x 32x32 out, BK=64 ----
__device__ __forceinline__ void gemm_tile_body(
    const unsigned short* __restrict__ A, const unsigned short* __restrict__ W,
    f32x4 acc[2][2], int bm, int bn, int tid) {
  __shared__ unsigned short As[BM][LPAD];
  __shared__ unsigned short Ws[BN][LPAD];
  const int w = tid >> 6, lane = tid & 63;
  const int quad = lane >> 4, r = lane & 15;
  const int wm = (w >> 1) * 32, wn = (w & 1) * 32;
  const int lr = tid >> 3;          // 0..31
  const int lc = (tid & 7) * 8;     // 0..56
  const unsigned short* Abase = A + (size_t)(bm * BM + lr) * C_DIM + lc;
  const unsigned short* Wbase = W + (size_t)(bn * BN + lr) * C_DIM + lc;
  for (int kb = 0; kb < C_DIM; kb += BK) {
    *reinterpret_cast<short8*>(&As[lr][lc]) =
        *reinterpret_cast<const short8*>(Abase + kb);
    *reinterpret_cast<short8*>(&As[lr + 32][lc]) =
        *reinterpret_cast<const short8*>(Abase + kb + 32 * C_DIM);
    *reinterpret_cast<short8*>(&Ws[lr][lc]) =
        *reinterpret_cast<const short8*>(Wbase + kb);
    *reinterpret_cast<short8*>(&Ws[lr + 32][lc]) =
        *reinterpret_cast<const short8*>(Wbase + kb + 32 * C_DIM);
    __syncthreads();
    #pragma unroll
    for (int ks = 0; ks < BK; ks += 32) {
      short8 a0 = *reinterpret_cast<const short8*>(&As[wm + r][ks + quad * 8]);
      short8 a1 = *reinterpret_cast<const short8*>(&As[wm + 16 + r][ks + quad * 8]);
      short8 b0 = *reinterpret_cast<const short8*>(&Ws[wn + r][ks + quad * 8]);
      short8 b1 = *reinterpret_cast<const short8*>(&Ws[wn + 16 + r][ks + quad * 8]);
      acc[0][0] = __builtin_amdgcn_mfma_f32_16x16x32_bf16(a0, b0, acc[0][0], 0, 0, 0);
      acc[0][1] = __builtin_amdgcn_mfma_f32_16x16x32_bf16(a0, b1, acc[0][1], 0, 0, 0);
      acc[1][0] = __builtin_amdgcn_mfma_f32_16x16x32_bf16(a1, b0, acc[1][0], 0, 0, 0);
      acc[1][1] = __builtin_amdgcn_mfma_f32_16x16x32_bf16(a1, b1, acc[1][1], 0, 0, 0);
    }
    __syncthreads();
  }
}

// ---- fused QKV projection: 3 GEMMs in one launch; W selected by block range ----
__global__ __launch_bounds__(256) void gemm_qkv_kernel(
    const unsigned short* __restrict__ A,
    const unsigned short* __restrict__ Wq, const unsigned short* __restrict__ Wk,
    const unsigned short* __restrict__ Wv,
    const float* __restrict__ bq, const float* __restrict__ bk,
    const float* __restrict__ bv,
    unsigned short* __restrict__ qo, unsigned short* __restrict__ ko,
    unsigned short* __restrict__ vo) {
  const int per = (T_DIM / BM) * (C_DIM / BN);  // 512
  const int which = blockIdx.x / per;
  const int rem = blockIdx.x % per;
  const int bm = rem / (C_DIM / BN);
  const int bn = rem % (C_DIM / BN);
  const unsigned short* W = (which == 0) ? Wq : (which == 1) ? Wk : Wv;
  const float* bias = (which == 0) ? bq : (which == 1) ? bk : bv;
  unsigned short* out = (which == 0) ? qo : (which == 1) ? ko : vo;
  const int tid = threadIdx.x;
  f32x4 acc[2][2] = {};
  gemm_tile_body(A, W, acc, bm, bn, tid);
  const int w = tid >> 6, lane = tid & 63;
  const int quad = lane >> 4, r = lane & 15;
  const int wm = (w >> 1) * 32, wn = (w & 1) * 32;
  #pragma unroll
  for (int mi = 0; mi < 2; ++mi) {
    #pragma unroll
    for (int ni = 0; ni < 2; ++ni) {
      const int col = bn * BN + wn + ni * 16 + r;
      const float bf = bias[col];
      #pragma unroll
      for (int i = 0; i < 4; ++i) {
        const int row = bm * BM + wm + mi * 16 + quad * 4 + i;
        out[(size_t)row * C_DIM + col] = f2bfu(acc[mi][ni][i] + bf);
      }
    }
  }
}

// ---- output projection GEMM, fp32 out ----
__global__ __launch_bounds__(256) void gemm_tile_f32_kernel(
    const unsigned short* __restrict__ A, const unsigned short* __restrict__ W,
    const float* __restrict__ bias, float* __restrict__ out) {
  const int tid = threadIdx.x;
  const int bm = blockIdx.x / (C_DIM / BN);
  const int bn = blockIdx.x % (C_DIM / BN);
  f32x4 acc[2][2] = {};
  gemm_tile_body(A, W, acc, bm, bn, tid);
  const int w = tid >> 6, lane = tid & 63;
  const int quad = lane >> 4, r = lane & 15;
  const int wm = (w >> 1) * 32, wn = (w & 1) * 32;
  #pragma unroll
  for (int mi = 0; mi < 2; ++mi) {
    #pragma unroll
    for (int ni = 0; ni < 2; ++ni) {
      const int col = bn * BN + wn + ni * 16 + r;
      const float bf = bias[col];
      #pragma unroll
      for (int i = 0; i < 4; ++i) {
        const int row = bm * BM + wm + mi * 16 + quad * 4 + i;
        out[(size_t)row * C_DIM + col] = acc[mi][ni][i] + bf;
      }
    }
  }
}

// ---- sparse attention v2: block per (t, head-group of 4), one wave per head ----
__global__ __launch_bounds__(256) void attn_kernel(
    const unsigned short* __restrict__ q, const unsigned short* __restrict__ k,
    const unsigned short* __restrict__ v, const int* __restrict__ topk,
    unsigned short* __restrict__ attn_out) {
  __shared__ int idx_s[KSP];
  __shared__ float q_s[4][HS];
  __shared__ float p_s[4][KSP];
  const int t = blockIdx.x >> 2;
  const int hg = blockIdx.x & 3;
  const int tid = threadIdx.x;
  const int w = tid >> 6, lane = tid & 63;
  const int h = hg * 4 + w;  // this wave's head
  if (tid < KSP) {
    int s = topk[(size_t)t * KSP + tid];
    idx_s[tid] = (s < 0) ? 0 : (s > t ? t : s);  // valid set is [0, t]
  }
  q_s[w][lane] = bfu2f(q[(size_t)t * C_DIM + h * HS + lane]);
  __syncthreads();
  // phase 1: lane j owns key j
  const int my_idx = idx_s[lane];
  const unsigned short* krow = k + (size_t)my_idx * C_DIM + h * HS;
  float lg = 0.f;
  #pragma unroll
  for (int c8 = 0; c8 < 8; ++c8) {
    uint4 raw = *reinterpret_cast<const uint4*>(krow + c8 * 8);
    unsigned uu[4] = {raw.x, raw.y, raw.z, raw.w};
    #pragma unroll
    for (int p = 0; p < 4; ++p) {
      float lo = __builtin_bit_cast(float, uu[p] << 16);
      float hi = __builtin_bit_cast(float, uu[p] & 0xffff0000u);
      lg += q_s[w][c8 * 8 + 2 * p] * lo;
      lg += q_s[w][c8 * 8 + 2 * p + 1] * hi;
    }
  }
  lg *= 0.125f;  // 1/sqrt(64)
  float m = lg;
  #pragma unroll
  for (int o = 32; o; o >>= 1) m = fmaxf(m, __shfl_xor(m, o));
  float pexp = __expf(lg - m);
  float s = pexp;
  #pragma unroll
  for (int o = 32; o; o >>= 1) s += __shfl_xor(s, o);
  p_s[w][lane] = pexp / s;
  __syncthreads();
  // phase 2: lane owns output channel `lane` of head h; probs via LDS broadcast
  float acc = 0.f;
  const unsigned short* vbase = v + h * HS + lane;
  #pragma unroll 8
  for (int j = 0; j < KSP; ++j) {
    acc += p_s[w][j] * bfu2f(vbase[(size_t)idx_s[j] * C_DIM]);
  }
  attn_out[(size_t)t * C_DIM + h * HS + lane] = f2bfu(acc);
}

extern "C" void kernel_launch(void* const* d_in, const int* in_sizes, int n_in,
                              void* d_out, int out_size, void* d_ws, size_t ws_size,
                              hipStream_t stream) {
  const float* x   = (const float*)d_in[0];
  const float* Wq  = (const float*)d_in[1];
  const float* bq  = (const float*)d_in[2];
  const float* Wk  = (const float*)d_in[3];
  const float* bk  = (const float*)d_in[4];
  const float* Wv  = (const float*)d_in[5];
  const float* bv  = (const float*)d_in[6];
  const float* Wo  = (const float*)d_in[7];
  const float* bo  = (const float*)d_in[8];
  const float* Wks = (const float*)d_in[9];
  const float* bks = (const float*)d_in[10];
  float* out = (float*)d_out;

  char* ws = (char*)d_ws;
  size_t off = 0;
  float* scores = (float*)(ws + off); off += 8192;
  int*   sorted = (int*)(ws + off);   off += 8192;
  int*   topk   = (int*)(ws + off);   off += (size_t)T_DIM * KSP * 4;
  unsigned short* xb  = (unsigned short*)(ws + off); off += (size_t)T_DIM * C_DIM * 2;
  unsigned short* Wqb = (unsigned short*)(ws + off); off += (size_t)C_DIM * C_DIM * 2;
  unsigned short* Wkb = (unsigned short*)(ws + off); off += (size_t)C_DIM * C_DIM * 2;
  unsigned short* Wvb = (unsigned short*)(ws + off); off += (size_t)C_DIM * C_DIM * 2;
  unsigned short* Wob = (unsigned short*)(ws + off); off += (size_t)C_DIM * C_DIM * 2;
  unsigned short* qb  = (unsigned short*)(ws + off); off += (size_t)T_DIM * C_DIM * 2;
  unsigned short* kb  = (unsigned short*)(ws + off); off += (size_t)T_DIM * C_DIM * 2;
  unsigned short* vb  = (unsigned short*)(ws + off); off += (size_t)T_DIM * C_DIM * 2;
  unsigned short* ab  = (unsigned short*)(ws + off); off += (size_t)T_DIM * C_DIM * 2;

  // fused bf16 conversion (x + 4 weights), 1.5M float4s -> 6144 blocks
  const int n4_total = (T_DIM * C_DIM + 4 * C_DIM * C_DIM) / 4;
  convert_all_kernel<<<n4_total / 256, 256, 0, stream>>>(
      x, Wq, Wk, Wv, Wo, xb, Wqb, Wkb, Wvb, Wob);

  // scores (fp32) -> rank-sort -> select
  scores_kernel<<<T_DIM / 4, 256, 0, stream>>>(x, Wks, bks, scores);
  rank_sort_kernel<<<T_DIM / 256, 256, 0, stream>>>(scores, sorted);
  select_topk_kernel<<<T_DIM / 4, 256, 0, stream>>>(sorted, topk);

  // fused QKV projection: 3 x 512 blocks
  gemm_qkv_kernel<<<3 * (T_DIM / BM) * (C_DIM / BN), 256, 0, stream>>>(
      xb, Wqb, Wkb, Wvb, bq, bk, bv, qb, kb, vb);

  // sparse attention: (t, head-group) grid
  attn_kernel<<<T_DIM * 4, 256, 0, stream>>>(qb, kb, vb, topk, ab);

  // output projection (fp32 out)
  gemm_tile_f32_kernel<<<(T_DIM / BM) * (C_DIM / BN), 256, 0, stream>>>(
      ab, Wob, bo, out);
}

// Round 7
// 236.878 us; speedup vs baseline: 2.8626x; 1.0324x over previous
//
#include <hip/hip_runtime.h>
#include <hip/hip_bf16.h>
#include <cstdint>
#include <cstddef>

#define T_DIM 2048
#define C_DIM 1024
#define NH 16
#define HS 64
#define KSP 64

// 128x64 GEMM tile, BK=64
#define GBM 128
#define GBN 64
#define GBK 64
#define GPAD 72  // 64+8 elems -> 144B row stride; frag-read bank alias = 2-way (free)

typedef short short8 __attribute__((ext_vector_type(8)));
typedef float f32x4 __attribute__((ext_vector_type(4)));

__device__ __forceinline__ float bfu2f(unsigned short u) {
  unsigned v = ((unsigned)u) << 16;
  return __builtin_bit_cast(float, v);
}
__device__ __forceinline__ unsigned short f2bfu(float f) {
  unsigned u = __builtin_bit_cast(unsigned, f);
  unsigned r = (u + 0x7fffu + ((u >> 16) & 1u)) >> 16;
  return (unsigned short)r;
}

// ---- fused float32 -> bf16 conversion of x + 4 weight matrices ----
__global__ __launch_bounds__(256) void convert_all_kernel(
    const float* __restrict__ x, const float* __restrict__ Wq,
    const float* __restrict__ Wk, const float* __restrict__ Wv,
    const float* __restrict__ Wo,
    unsigned short* __restrict__ xb, unsigned short* __restrict__ Wqb,
    unsigned short* __restrict__ Wkb, unsigned short* __restrict__ Wvb,
    unsigned short* __restrict__ Wob) {
  const int i = blockIdx.x * 256 + threadIdx.x;
  const int NX4 = T_DIM * C_DIM / 4;
  const int NW4 = C_DIM * C_DIM / 4;
  const float* src;
  unsigned short* dst;
  int j = i;
  if (j < NX4) { src = x; dst = xb; }
  else {
    j -= NX4;
    int w = j / NW4;
    j -= w * NW4;
    src = (w == 0) ? Wq : (w == 1) ? Wk : (w == 2) ? Wv : Wo;
    dst = (w == 0) ? Wqb : (w == 1) ? Wkb : (w == 2) ? Wvb : Wob;
  }
  float4 f = reinterpret_cast<const float4*>(src)[j];
  ushort4 o;
  o.x = f2bfu(f.x); o.y = f2bfu(f.y); o.z = f2bfu(f.z); o.w = f2bfu(f.w);
  reinterpret_cast<ushort4*>(dst)[j] = o;
}

// ---- key_scores[t] = x[t,:]·Wks + bks  (fp32; one wave per row) ----
__global__ __launch_bounds__(256) void scores_kernel(
    const float* __restrict__ x, const float* __restrict__ Wks,
    const float* __restrict__ bks, float* __restrict__ scores) {
  const int t = blockIdx.x * 4 + (threadIdx.x >> 6);
  const int lane = threadIdx.x & 63;
  const float* xrow = x + (size_t)t * C_DIM;
  float acc = 0.f;
  #pragma unroll 4
  for (int i = lane; i < C_DIM; i += 64)
    acc += xrow[i] * Wks[i];
  #pragma unroll
  for (int o = 32; o; o >>= 1) acc += __shfl_xor(acc, o);
  if (lane == 0) scores[t] = acc + bks[0];
}

// ---- rank-by-counting sort: sorted[rank_i] = i ----
__global__ __launch_bounds__(256) void rank_sort_kernel(
    const float* __restrict__ scores, int* __restrict__ sorted_idx) {
  __shared__ float ss[T_DIM];
  const int tid = threadIdx.x;
  const int i = blockIdx.x * 256 + tid;
  for (int j = tid; j < T_DIM; j += 256) ss[j] = scores[j];
  __syncthreads();
  const float si = ss[i];
  int rank = 0;
  #pragma unroll 8
  for (int j = 0; j < T_DIM; ++j) {
    float sj = ss[j];
    rank += (int)((sj > si) || (sj == si && j < i));
  }
  sorted_idx[rank] = i;
}

// ---- per-t top-64 selection: one wave per t, ballot + prefix-popcount ----
__global__ __launch_bounds__(256) void select_topk_kernel(
    const int* __restrict__ sorted_idx, int* __restrict__ topk) {
  __shared__ int ss[T_DIM];
  const int tid = threadIdx.x;
  for (int i = tid; i < T_DIM; i += 256) {
    int s = sorted_idx[i];
    ss[i] = (s < 0) ? 0 : (s > T_DIM - 1 ? T_DIM - 1 : s);
  }
  __syncthreads();
  const int t = blockIdx.x * 4 + (tid >> 6);
  const int lane = tid & 63;
  if (t <= 63) {
    topk[(size_t)t * KSP + lane] = (lane < t) ? lane : t;
  } else {
    const unsigned long long lt_mask = (1ull << lane) - 1ull;
    int count = 0;
    for (int chunk = 0; chunk < T_DIM / 64 && count < KSP; ++chunk) {
      int s = ss[chunk * 64 + lane];
      bool ok = (s <= t);
      unsigned long long m = __ballot(ok);
      int pos = count + __popcll(m & lt_mask);
      if (ok && pos < KSP) topk[(size_t)t * KSP + pos] = s;
      count += __popcll(m);
    }
  }
}

// ---- GEMM body: 128x64 tile, BK=64; 4 waves, each 64x32 (4x2 accs of 16x16) ----
__device__ __forceinline__ void gemm_body_128x64(
    const unsigned short* __restrict__ A, const unsigned short* __restrict__ W,
    f32x4 acc[4][2], int bm, int bn, int tid) {
  __shared__ unsigned short As[GBM][GPAD];  // 18 KB
  __shared__ unsigned short Ws[GBN][GPAD];  // 9 KB
  const int w = tid >> 6, lane = tid & 63;
  const int quad = lane >> 4, r = lane & 15;
  const int wm = (w >> 1) * 64, wn = (w & 1) * 32;
  const int s_row = tid >> 3;          // 0..31
  const int s_ke = (tid & 7) * 8;      // element offset 0..56
  const unsigned short* Abase = A + (size_t)(bm * GBM + s_row) * C_DIM + s_ke;
  const unsigned short* Wbase = W + (size_t)(bn * GBN + s_row) * C_DIM + s_ke;
  for (int kb = 0; kb < C_DIM; kb += GBK) {
    #pragma unroll
    for (int i = 0; i < 4; ++i)
      *reinterpret_cast<short8*>(&As[s_row + 32 * i][s_ke]) =
          *reinterpret_cast<const short8*>(Abase + kb + (size_t)(32 * i) * C_DIM);
    #pragma unroll
    for (int i = 0; i < 2; ++i)
      *reinterpret_cast<short8*>(&Ws[s_row + 32 * i][s_ke]) =
          *reinterpret_cast<const short8*>(Wbase + kb + (size_t)(32 * i) * C_DIM);
    __syncthreads();
    #pragma unroll
    for (int ks = 0; ks < 2; ++ks) {
      short8 af[4], bf[2];
      #pragma unroll
      for (int mi = 0; mi < 4; ++mi)
        af[mi] = *reinterpret_cast<const short8*>(&As[wm + mi * 16 + r][ks * 32 + quad * 8]);
      #pragma unroll
      for (int ni = 0; ni < 2; ++ni)
        bf[ni] = *reinterpret_cast<const short8*>(&Ws[wn + ni * 16 + r][ks * 32 + quad * 8]);
      #pragma unroll
      for (int mi = 0; mi < 4; ++mi)
        #pragma unroll
        for (int ni = 0; ni < 2; ++ni)
          acc[mi][ni] = __builtin_amdgcn_mfma_f32_16x16x32_bf16(af[mi], bf[ni], acc[mi][ni], 0, 0, 0);
    }
    __syncthreads();
  }
}

// ---- fused QKV projection: 3 GEMMs in one launch ----
__global__ __launch_bounds__(256) void gemm_qkv_kernel(
    const unsigned short* __restrict__ A,
    const unsigned short* __restrict__ Wq, const unsigned short* __restrict__ Wk,
    const unsigned short* __restrict__ Wv,
    const float* __restrict__ bq, const float* __restrict__ bk,
    const float* __restrict__ bv,
    unsigned short* __restrict__ qo, unsigned short* __restrict__ ko,
    unsigned short* __restrict__ vo) {
  const int per = (T_DIM / GBM) * (C_DIM / GBN);  // 256
  const int which = blockIdx.x / per;
  const int rem = blockIdx.x % per;
  const int bm = rem / (C_DIM / GBN);
  const int bn = rem % (C_DIM / GBN);
  const unsigned short* W = (which == 0) ? Wq : (which == 1) ? Wk : Wv;
  const float* bias = (which == 0) ? bq : (which == 1) ? bk : bv;
  unsigned short* out = (which == 0) ? qo : (which == 1) ? ko : vo;
  const int tid = threadIdx.x;
  f32x4 acc[4][2] = {};
  gemm_body_128x64(A, W, acc, bm, bn, tid);
  const int w = tid >> 6, lane = tid & 63;
  const int quad = lane >> 4, r = lane & 15;
  const int wm = (w >> 1) * 64, wn = (w & 1) * 32;
  #pragma unroll
  for (int mi = 0; mi < 4; ++mi) {
    #pragma unroll
    for (int ni = 0; ni < 2; ++ni) {
      const int col = bn * GBN + wn + ni * 16 + r;
      const float bf = bias[col];
      #pragma unroll
      for (int i = 0; i < 4; ++i) {
        const int row = bm * GBM + wm + mi * 16 + quad * 4 + i;
        out[(size_t)row * C_DIM + col] = f2bfu(acc[mi][ni][i] + bf);
      }
    }
  }
}

// ---- output projection GEMM, fp32 out ----
__global__ __launch_bounds__(256) void gemm_o_f32_kernel(
    const unsigned short* __restrict__ A, const unsigned short* __restrict__ W,
    const float* __restrict__ bias, float* __restrict__ out) {
  const int tid = threadIdx.x;
  const int bm = blockIdx.x / (C_DIM / GBN);
  const int bn = blockIdx.x % (C_DIM / GBN);
  f32x4 acc[4][2] = {};
  gemm_body_128x64(A, W, acc, bm, bn, tid);
  const int w = tid >> 6, lane = tid & 63;
  const int quad = lane >> 4, r = lane & 15;
  const int wm = (w >> 1) * 64, wn = (w & 1) * 32;
  #pragma unroll
  for (int mi = 0; mi < 4; ++mi) {
    #pragma unroll
    for (int ni = 0; ni < 2; ++ni) {
      const int col = bn * GBN + wn + ni * 16 + r;
      const float bf = bias[col];
      #pragma unroll
      for (int i = 0; i < 4; ++i) {
        const int row = bm * GBM + wm + mi * 16 + quad * 4 + i;
        out[(size_t)row * C_DIM + col] = acc[mi][ni][i] + bf;
      }
    }
  }
}

// ---- sparse attention v3: block per (t, head-group), one wave per head,
// zero block barriers, 4 accumulators per phase ----
__global__ __launch_bounds__(256) void attn_kernel(
    const unsigned short* __restrict__ q, const unsigned short* __restrict__ k,
    const unsigned short* __restrict__ v, const int* __restrict__ topk,
    unsigned short* __restrict__ attn_out) {
  __shared__ int off_s[4][KSP];     // per-wave: row offsets (idx * C_DIM)
  __shared__ float q_s[4][HS];      // per-wave: q vector
  __shared__ float p_s[4][KSP];     // per-wave: probs
  const int t = blockIdx.x >> 2;
  const int hg = blockIdx.x & 3;
  const int tid = threadIdx.x;
  const int w = tid >> 6, lane = tid & 63;
  const int h = hg * 4 + w;
  int s = topk[(size_t)t * KSP + lane];
  s = (s < 0) ? 0 : (s > t ? t : s);  // valid set is [0, t]
  const int my_off = s * C_DIM;
  off_s[w][lane] = my_off;
  q_s[w][lane] = bfu2f(q[(size_t)t * C_DIM + h * HS + lane]);
  __builtin_amdgcn_wave_barrier();
  // phase 1: lane j owns key j; 4 independent accumulators
  const unsigned short* krow = k + my_off + h * HS;
  float l0 = 0.f, l1 = 0.f, l2 = 0.f, l3 = 0.f;
  #pragma unroll
  for (int c8 = 0; c8 < 8; ++c8) {
    uint4 raw = *reinterpret_cast<const uint4*>(krow + c8 * 8);
    unsigned uu[4] = {raw.x, raw.y, raw.z, raw.w};
    l0 += q_s[w][c8 * 8 + 0] * __builtin_bit_cast(float, uu[0] << 16)
        + q_s[w][c8 * 8 + 1] * __builtin_bit_cast(float, uu[0] & 0xffff0000u);
    l1 += q_s[w][c8 * 8 + 2] * __builtin_bit_cast(float, uu[1] << 16)
        + q_s[w][c8 * 8 + 3] * __builtin_bit_cast(float, uu[1] & 0xffff0000u);
    l2 += q_s[w][c8 * 8 + 4] * __builtin_bit_cast(float, uu[2] << 16)
        + q_s[w][c8 * 8 + 5] * __builtin_bit_cast(float, uu[2] & 0xffff0000u);
    l3 += q_s[w][c8 * 8 + 6] * __builtin_bit_cast(float, uu[3] << 16)
        + q_s[w][c8 * 8 + 7] * __builtin_bit_cast(float, uu[3] & 0xffff0000u);
  }
  float lg = ((l0 + l1) + (l2 + l3)) * 0.125f;  // 1/sqrt(64)
  float m = lg;
  #pragma unroll
  for (int o = 32; o; o >>= 1) m = fmaxf(m, __shfl_xor(m, o));
  float pexp = __expf(lg - m);
  float sum = pexp;
  #pragma unroll
  for (int o = 32; o; o >>= 1) sum += __shfl_xor(sum, o);
  p_s[w][lane] = pexp / sum;
  __builtin_amdgcn_wave_barrier();
  // phase 2: lane owns channel `lane`; 16 loads in flight, 4 accumulators
  const unsigned short* vbase = v + h * HS + lane;
  float a0 = 0.f, a1 = 0.f, a2 = 0.f, a3 = 0.f;
  #pragma unroll 4
  for (int j = 0; j < KSP; j += 4) {
    a0 += p_s[w][j + 0] * bfu2f(vbase[off_s[w][j + 0]]);
    a1 += p_s[w][j + 1] * bfu2f(vbase[off_s[w][j + 1]]);
    a2 += p_s[w][j + 2] * bfu2f(vbase[off_s[w][j + 2]]);
    a3 += p_s[w][j + 3] * bfu2f(vbase[off_s[w][j + 3]]);
  }
  attn_out[(size_t)t * C_DIM + h * HS + lane] = f2bfu((a0 + a1) + (a2 + a3));
}

extern "C" void kernel_launch(void* const* d_in, const int* in_sizes, int n_in,
                              void* d_out, int out_size, void* d_ws, size_t ws_size,
                              hipStream_t stream) {
  const float* x   = (const float*)d_in[0];
  const float* Wq  = (const float*)d_in[1];
  const float* bq  = (const float*)d_in[2];
  const float* Wk  = (const float*)d_in[3];
  const float* bk  = (const float*)d_in[4];
  const float* Wv  = (const float*)d_in[5];
  const float* bv  = (const float*)d_in[6];
  const float* Wo  = (const float*)d_in[7];
  const float* bo  = (const float*)d_in[8];
  const float* Wks = (const float*)d_in[9];
  const float* bks = (const float*)d_in[10];
  float* out = (float*)d_out;

  char* ws = (char*)d_ws;
  size_t off = 0;
  float* scores = (float*)(ws + off); off += 8192;
  int*   sorted = (int*)(ws + off);   off += 8192;
  int*   topk   = (int*)(ws + off);   off += (size_t)T_DIM * KSP * 4;
  unsigned short* xb  = (unsigned short*)(ws + off); off += (size_t)T_DIM * C_DIM * 2;
  unsigned short* Wqb = (unsigned short*)(ws + off); off += (size_t)C_DIM * C_DIM * 2;
  unsigned short* Wkb = (unsigned short*)(ws + off); off += (size_t)C_DIM * C_DIM * 2;
  unsigned short* Wvb = (unsigned short*)(ws + off); off += (size_t)C_DIM * C_DIM * 2;
  unsigned short* Wob = (unsigned short*)(ws + off); off += (size_t)C_DIM * C_DIM * 2;
  unsigned short* qb  = (unsigned short*)(ws + off); off += (size_t)T_DIM * C_DIM * 2;
  unsigned short* kb  = (unsigned short*)(ws + off); off += (size_t)T_DIM * C_DIM * 2;
  unsigned short* vb  = (unsigned short*)(ws + off); off += (size_t)T_DIM * C_DIM * 2;
  unsigned short* ab  = (unsigned short*)(ws + off); off += (size_t)T_DIM * C_DIM * 2;

  const int n4_total = (T_DIM * C_DIM + 4 * C_DIM * C_DIM) / 4;
  convert_all_kernel<<<n4_total / 256, 256, 0, stream>>>(
      x, Wq, Wk, Wv, Wo, xb, Wqb, Wkb, Wvb, Wob);

  scores_kernel<<<T_DIM / 4, 256, 0, stream>>>(x, Wks, bks, scores);
  rank_sort_kernel<<<T_DIM / 256, 256, 0, stream>>>(scores, sorted);
  select_topk_kernel<<<T_DIM / 4, 256, 0, stream>>>(sorted, topk);

  // fused QKV projection: 3 x 256 blocks of 128x64
  gemm_qkv_kernel<<<3 * (T_DIM / GBM) * (C_DIM / GBN), 256, 0, stream>>>(
      xb, Wqb, Wkb, Wvb, bq, bk, bv, qb, kb, vb);

  // sparse attention: (t, head-group) grid
  attn_kernel<<<T_DIM * 4, 256, 0, stream>>>(qb, kb, vb, topk, ab);

  // output projection (fp32 out): 256 blocks of 128x64
  gemm_o_f32_kernel<<<(T_DIM / GBM) * (C_DIM / GBN), 256, 0, stream>>>(
      ab, Wob, bo, out);
}